// Round 1
// baseline (1341.392 us; speedup 1.0000x reference)
//
#include <hip/hip_runtime.h>

// DyHuCoG: out = (E + A*E + A*(A*E)) / 3
// E: [N,32] f32, A: COO (vals f32, row i32, col i32), N=100001, nE=6400000.
//
// Baseline: atomic-scatter SpMM. One 32-lane group per edge, lane=dim.
//   y1 = A*E          (atomics into ws)
//   out = (E + y1)/3
//   out += (A*y1)/3   (atomics into out)

constexpr int D = 32;

__global__ void zero_f32(float* __restrict__ p, int n) {
    int i = blockIdx.x * blockDim.x + threadIdx.x;
    if (i < n) p[i] = 0.0f;
}

__global__ __launch_bounds__(256) void spmm_atomic(
    const int* __restrict__ row, const int* __restrict__ col,
    const float* __restrict__ vals, const float* __restrict__ x,
    float* __restrict__ y, int nEdges, float scale) {
    long long t = (long long)blockIdx.x * blockDim.x + threadIdx.x;
    int e = (int)(t >> 5);
    if (e >= nEdges) return;
    int d = (int)(t & 31);
    int r = row[e];
    int c = col[e];
    float v = vals[e] * scale;
    float g = v * x[(long long)c * D + d];
    atomicAdd(&y[(long long)r * D + d], g);
}

__global__ void combine_third(const float* __restrict__ emb,
                              const float* __restrict__ y1,
                              float* __restrict__ out, int n) {
    int i = blockIdx.x * blockDim.x + threadIdx.x;
    if (i < n) out[i] = (emb[i] + y1[i]) * (1.0f / 3.0f);
}

extern "C" void kernel_launch(void* const* d_in, const int* in_sizes, int n_in,
                              void* d_out, int out_size, void* d_ws, size_t ws_size,
                              hipStream_t stream) {
    const float* emb  = (const float*)d_in[0];
    const float* vals = (const float*)d_in[1];
    const int*   row  = (const int*)d_in[2];
    const int*   col  = (const int*)d_in[3];
    float* out = (float*)d_out;

    const int nElem  = in_sizes[0];        // N * 32
    const int nEdges = in_sizes[1];

    float* y1 = (float*)d_ws;              // nElem floats (12.8 MB)

    const int BLK = 256;
    // 1) y1 = 0
    zero_f32<<<(nElem + BLK - 1) / BLK, BLK, 0, stream>>>(y1, nElem);

    // 2) y1 = A * E
    {
        long long threads = (long long)nEdges * 32;
        int blocks = (int)((threads + BLK - 1) / BLK);
        spmm_atomic<<<blocks, BLK, 0, stream>>>(row, col, vals, emb, y1, nEdges, 1.0f);
    }

    // 3) out = (E + y1)/3
    combine_third<<<(nElem + BLK - 1) / BLK, BLK, 0, stream>>>(emb, y1, out, nElem);

    // 4) out += (A * y1)/3
    {
        long long threads = (long long)nEdges * 32;
        int blocks = (int)((threads + BLK - 1) / BLK);
        spmm_atomic<<<blocks, BLK, 0, stream>>>(row, col, vals, y1, out, nEdges, 1.0f / 3.0f);
    }
}

// Round 2
// 1079.479 us; speedup vs baseline: 1.2426x; 1.2426x over previous
//
#include <hip/hip_runtime.h>

// DyHuCoG: out = (E + A*E + A*(A*E)) / 3
// E: [N,32] f32, A: COO (vals f32, row i32, col i32), N=100001, nE=6400000.
//
// Strategy: build CSR on-device (histogram -> scan -> scatter packed
// (col,val) pairs), then both SpMM layers are gather-form (no atomics).
//   y1  = A * E
//   out = (E + y1 + A*y1) / 3   (layer 2 fused with combine)

constexpr int D = 32;
constexpr int CHUNK = 1024;   // elements per scan block (256 thr x 4)

// ---------------- utility ----------------
__global__ void zero_i32(int* __restrict__ p, int n) {
    int i = blockIdx.x * blockDim.x + threadIdx.x;
    if (i < n) p[i] = 0;
}
__global__ void zero_f32(float* __restrict__ p, int n) {
    int i = blockIdx.x * blockDim.x + threadIdx.x;
    if (i < n) p[i] = 0.0f;
}

// ---------------- CSR build ----------------
__global__ __launch_bounds__(256) void hist_rows(
    const int* __restrict__ row, int* __restrict__ cnt, int nEdges) {
    int e = blockIdx.x * blockDim.x + threadIdx.x;
    if (e < nEdges) atomicAdd(&cnt[row[e]], 1);
}

// per-chunk exclusive scan; writes chunk total to partials[blockIdx]
__global__ __launch_bounds__(256) void scan_chunk(
    const int* __restrict__ cnt, int* __restrict__ ptr,
    int* __restrict__ partials, int n) {
    __shared__ int s[256];
    int t = threadIdx.x;
    int base = blockIdx.x * CHUNK + t * 4;
    int a0 = (base + 0 < n) ? cnt[base + 0] : 0;
    int a1 = (base + 1 < n) ? cnt[base + 1] : 0;
    int a2 = (base + 2 < n) ? cnt[base + 2] : 0;
    int a3 = (base + 3 < n) ? cnt[base + 3] : 0;
    s[t] = a0 + a1 + a2 + a3;
    __syncthreads();
    for (int off = 1; off < 256; off <<= 1) {
        int v = 0;
        if (t >= off) v = s[t - off];
        __syncthreads();
        s[t] += v;
        __syncthreads();
    }
    int excl = (t == 0) ? 0 : s[t - 1];
    if (t == 255) partials[blockIdx.x] = s[255];
    if (base + 0 < n) ptr[base + 0] = excl;
    if (base + 1 < n) ptr[base + 1] = excl + a0;
    if (base + 2 < n) ptr[base + 2] = excl + a0 + a1;
    if (base + 3 < n) ptr[base + 3] = excl + a0 + a1 + a2;
}

// single-block exclusive scan of partials (nP <= 1024)
__global__ __launch_bounds__(1024) void scan_top(int* __restrict__ partials, int nP) {
    __shared__ int s[1024];
    int t = threadIdx.x;
    s[t] = (t < nP) ? partials[t] : 0;
    __syncthreads();
    for (int off = 1; off < 1024; off <<= 1) {
        int v = 0;
        if (t >= off) v = s[t - off];
        __syncthreads();
        s[t] += v;
        __syncthreads();
    }
    if (t < nP) partials[t] = (t == 0) ? 0 : s[t - 1];
}

// ptr[i] += partials[i/CHUNK]; cur[i] = ptr[i]; ptr[n] = nEdges
__global__ __launch_bounds__(256) void finalize_ptr(
    int* __restrict__ ptr, const int* __restrict__ partials,
    int* __restrict__ cur, int n, int nEdges) {
    int i = blockIdx.x * blockDim.x + threadIdx.x;
    if (i < n) {
        int v = ptr[i] + partials[i / CHUNK];
        ptr[i] = v;
        cur[i] = v;
    }
    if (i == 0) ptr[n] = nEdges;
}

__global__ __launch_bounds__(256) void scatter_edges(
    const int* __restrict__ row, const int* __restrict__ col,
    const float* __restrict__ vals, int* __restrict__ cur,
    int2* __restrict__ cv, int nEdges) {
    int e = blockIdx.x * blockDim.x + threadIdx.x;
    if (e >= nEdges) return;
    int r = row[e];
    int pos = atomicAdd(&cur[r], 1);
    int2 p;
    p.x = col[e];
    p.y = __float_as_int(vals[e]);
    cv[pos] = p;
}

// ---------------- gather-form SpMM ----------------
__global__ __launch_bounds__(256) void spmm_csr(
    const int* __restrict__ ptr, const int2* __restrict__ cv,
    const float* __restrict__ x, float* __restrict__ y, int nRows) {
    int g = (blockIdx.x * 256 + threadIdx.x) >> 5;
    if (g >= nRows) return;
    int lane = threadIdx.x & 31;
    int e = ptr[g], end = ptr[g + 1];
    float acc = 0.0f;
    for (; e + 4 <= end; e += 4) {
        int2 a = cv[e], b = cv[e + 1], c = cv[e + 2], d = cv[e + 3];
        float xa = x[(size_t)a.x * D + lane];
        float xb = x[(size_t)b.x * D + lane];
        float xc = x[(size_t)c.x * D + lane];
        float xd = x[(size_t)d.x * D + lane];
        acc += __int_as_float(a.y) * xa;
        acc += __int_as_float(b.y) * xb;
        acc += __int_as_float(c.y) * xc;
        acc += __int_as_float(d.y) * xd;
    }
    for (; e < end; ++e) {
        int2 a = cv[e];
        acc += __int_as_float(a.y) * x[(size_t)a.x * D + lane];
    }
    y[(size_t)g * D + lane] = acc;
}

// layer-2 fused: out = (emb + y1 + A*y1) / 3
__global__ __launch_bounds__(256) void spmm_csr_combine(
    const int* __restrict__ ptr, const int2* __restrict__ cv,
    const float* __restrict__ y1, const float* __restrict__ emb,
    float* __restrict__ out, int nRows) {
    int g = (blockIdx.x * 256 + threadIdx.x) >> 5;
    if (g >= nRows) return;
    int lane = threadIdx.x & 31;
    int e = ptr[g], end = ptr[g + 1];
    float acc = 0.0f;
    for (; e + 4 <= end; e += 4) {
        int2 a = cv[e], b = cv[e + 1], c = cv[e + 2], d = cv[e + 3];
        float xa = y1[(size_t)a.x * D + lane];
        float xb = y1[(size_t)b.x * D + lane];
        float xc = y1[(size_t)c.x * D + lane];
        float xd = y1[(size_t)d.x * D + lane];
        acc += __int_as_float(a.y) * xa;
        acc += __int_as_float(b.y) * xb;
        acc += __int_as_float(c.y) * xc;
        acc += __int_as_float(d.y) * xd;
    }
    for (; e < end; ++e) {
        int2 a = cv[e];
        acc += __int_as_float(a.y) * y1[(size_t)a.x * D + lane];
    }
    size_t idx = (size_t)g * D + lane;
    out[idx] = (emb[idx] + y1[idx] + acc) * (1.0f / 3.0f);
}

// ---------------- fallback (round-0 atomic path) ----------------
__global__ __launch_bounds__(256) void spmm_atomic(
    const int* __restrict__ row, const int* __restrict__ col,
    const float* __restrict__ vals, const float* __restrict__ x,
    float* __restrict__ y, int nEdges, float scale) {
    long long t = (long long)blockIdx.x * blockDim.x + threadIdx.x;
    int e = (int)(t >> 5);
    if (e >= nEdges) return;
    int d = (int)(t & 31);
    float g = vals[e] * scale * x[(long long)col[e] * D + d];
    atomicAdd(&y[(long long)row[e] * D + d], g);
}
__global__ void combine_third(const float* __restrict__ emb,
                              const float* __restrict__ y1,
                              float* __restrict__ out, int n) {
    int i = blockIdx.x * blockDim.x + threadIdx.x;
    if (i < n) out[i] = (emb[i] + y1[i]) * (1.0f / 3.0f);
}

extern "C" void kernel_launch(void* const* d_in, const int* in_sizes, int n_in,
                              void* d_out, int out_size, void* d_ws, size_t ws_size,
                              hipStream_t stream) {
    const float* emb  = (const float*)d_in[0];
    const float* vals = (const float*)d_in[1];
    const int*   row  = (const int*)d_in[2];
    const int*   col  = (const int*)d_in[3];
    float* out = (float*)d_out;

    const int nElem  = in_sizes[0];          // N * 32
    const int nEdges = in_sizes[1];
    const int n      = nElem / D;            // 100001
    const int BLK = 256;

    // workspace layout (bytes)
    size_t off_ptr  = 0;                                   // (n+1) ints
    size_t off_cur  = off_ptr + (size_t)(n + 1) * 4;       // n ints
    size_t off_part = off_cur + (size_t)n * 4;             // 1024 ints
    size_t off_cv   = (off_part + 1024 * 4 + 7) & ~(size_t)7;  // E int2
    size_t off_y1   = off_cv + (size_t)nEdges * 8;         // nElem floats
    size_t need     = off_y1 + (size_t)nElem * 4;

    if (ws_size < need) {
        // fallback: atomic-scatter path
        float* y1 = (float*)d_ws;
        zero_f32<<<(nElem + BLK - 1) / BLK, BLK, 0, stream>>>(y1, nElem);
        long long threads = (long long)nEdges * 32;
        int blocks = (int)((threads + BLK - 1) / BLK);
        spmm_atomic<<<blocks, BLK, 0, stream>>>(row, col, vals, emb, y1, nEdges, 1.0f);
        combine_third<<<(nElem + BLK - 1) / BLK, BLK, 0, stream>>>(emb, y1, out, nElem);
        spmm_atomic<<<blocks, BLK, 0, stream>>>(row, col, vals, y1, out, nEdges, 1.0f / 3.0f);
        return;
    }

    char* ws = (char*)d_ws;
    int*   ptr      = (int*)(ws + off_ptr);
    int*   cur      = (int*)(ws + off_cur);   // doubles as histogram counts
    int*   partials = (int*)(ws + off_part);
    int2*  cv       = (int2*)(ws + off_cv);
    float* y1       = (float*)(ws + off_y1);

    const int nChunks = (n + CHUNK - 1) / CHUNK;   // 98 for N=100001

    // 1) histogram row counts into cur
    zero_i32<<<(n + BLK - 1) / BLK, BLK, 0, stream>>>(cur, n);
    hist_rows<<<(nEdges + BLK - 1) / BLK, BLK, 0, stream>>>(row, cur, nEdges);

    // 2) exclusive scan -> ptr
    scan_chunk<<<nChunks, BLK, 0, stream>>>(cur, ptr, partials, n);
    scan_top<<<1, 1024, 0, stream>>>(partials, nChunks);
    finalize_ptr<<<(n + BLK - 1) / BLK, BLK, 0, stream>>>(ptr, partials, cur, n, nEdges);

    // 3) scatter packed (col,val) into CSR order
    scatter_edges<<<(nEdges + BLK - 1) / BLK, BLK, 0, stream>>>(row, col, vals, cur, cv, nEdges);

    // 4) y1 = A * E
    int rowBlocks = (n * 32 + BLK - 1) / BLK;
    spmm_csr<<<rowBlocks, BLK, 0, stream>>>(ptr, cv, emb, y1, n);

    // 5) out = (E + y1 + A*y1)/3
    spmm_csr_combine<<<rowBlocks, BLK, 0, stream>>>(ptr, cv, y1, emb, out, n);
}